// Round 4
// baseline (596.870 us; speedup 1.0000x reference)
//
#include <hip/hip_runtime.h>
#include <hip/hip_bf16.h>

// EdgewiseReduce: out[n, :] = sum_{e : dst[e]==n} edge_data[e, :] * 0.5
// E = 1.6M, D = 32, N = 100K.
//
// History:
//  R1: 51.2M f32 global atomics -> 819 MB of 16B txns, 647 us (atomic-bound).
//  R2: counting sort; random 4B scatter -> 106 MB line writebacks, 494 us.
//  R3: LDS privatization, every block scans all dsts -> 1.6 GB L3 traffic,
//      latency-bound at 4.2 TB/s effective, 378 us.
// R4: two-level bucketing. dst array is read O(E), not O(E*blocks); the id
// scatter goes through per-block LDS cursors into per-(block,bucket)
// contiguous regions so L2 write-combines full lines; the gather reads each
// 128B row exactly once into a 128-node LDS accumulator. ~243 MB total HBM.

#define D 32
#define FACTOR 0.5f
#define BSHIFT 7                 // 128 nodes per bucket
#define BNODES (1 << BSHIFT)

// ---------- K1: global bucket histogram ----------
__global__ void hist_kernel(const int* __restrict__ dst, int* __restrict__ ghist,
                            int E, int N, int nb) {
  extern __shared__ int lhist[];
  for (int i = threadIdx.x; i < nb; i += blockDim.x) lhist[i] = 0;
  __syncthreads();
  for (int e = blockIdx.x * blockDim.x + threadIdx.x; e < E;
       e += gridDim.x * blockDim.x) {
    int d = dst[e];
    if ((unsigned)d < (unsigned)N) atomicAdd(&lhist[d >> BSHIFT], 1);
  }
  __syncthreads();
  for (int i = threadIdx.x; i < nb; i += blockDim.x)
    if (lhist[i]) atomicAdd(&ghist[i], lhist[i]);
}

// ---------- K2: exclusive scan over nb (<=1024) buckets, one block ----------
__global__ void scan_kernel(const int* __restrict__ ghist, int* __restrict__ bases,
                            int* __restrict__ cursor, int nb) {
  __shared__ int buf[1024];
  int x = threadIdx.x;
  int v = (x < nb) ? ghist[x] : 0;
  buf[x] = v;
  __syncthreads();
  for (int off = 1; off < 1024; off <<= 1) {
    int t = (x >= off) ? buf[x - off] : 0;
    __syncthreads();
    buf[x] += t;
    __syncthreads();
  }
  if (x < nb) {
    int b = buf[x] - v;
    bases[x] = b;
    cursor[x] = b;
  }
}

// ---------- K3: per-block reserve + scatter packed ids ----------
__global__ void scatter_kernel(const int* __restrict__ dst, int* __restrict__ gcursor,
                               int* __restrict__ order, int E, int N, int nb,
                               int chunk) {
  extern __shared__ int sm[];
  int* lhist = sm;            // [nb]
  int* lcur = sm + nb;        // [nb]
  int lo = blockIdx.x * chunk;
  int hiE = min(lo + chunk, E);

  for (int i = threadIdx.x; i < nb; i += blockDim.x) lhist[i] = 0;
  __syncthreads();
  for (int e = lo + threadIdx.x; e < hiE; e += blockDim.x) {
    int d = dst[e];
    if ((unsigned)d < (unsigned)N) atomicAdd(&lhist[d >> BSHIFT], 1);
  }
  __syncthreads();
  for (int i = threadIdx.x; i < nb; i += blockDim.x) {
    int c = lhist[i];
    lcur[i] = c ? atomicAdd(&gcursor[i], c) : 0;
  }
  __syncthreads();
  for (int e = lo + threadIdx.x; e < hiE; e += blockDim.x) {
    int d = dst[e];
    if ((unsigned)d < (unsigned)N) {
      int pos = atomicAdd(&lcur[d >> BSHIFT], 1);
      order[pos] = (e << BSHIFT) | (d & (BNODES - 1));  // e<2^24, fits
    }
  }
}

// ---------- K4: gather-reduce per bucket ----------
#define K4_THREADS 512
__global__ __launch_bounds__(K4_THREADS)
void gather_kernel(const float4* __restrict__ data, const int* __restrict__ order,
                   const int* __restrict__ bases, const int* __restrict__ ghist,
                   float4* __restrict__ out, int N) {
  __shared__ float acc[BNODES * 33];   // stride 33: bank = (dl + 4*jq + c) % 32
  int b = blockIdx.x;
  int base = bases[b];
  int count = ghist[b];
  int lo = b << BSHIFT;

  for (int i = threadIdx.x; i < BNODES * 33; i += K4_THREADS) acc[i] = 0.f;
  __syncthreads();

  int q = threadIdx.x & 7;        // float4 slot within row
  int row = threadIdx.x >> 3;     // 0..63 concurrent rows
  int i = base + row;
  int end = base + count;
  // 2-way unroll: two independent load chains in flight per thread.
  for (; i + 64 < end; i += 128) {
    int pk0 = order[i];
    int pk1 = order[i + 64];
    float4 v0 = data[(size_t)(pk0 >> BSHIFT) * 8 + q];
    float4 v1 = data[(size_t)(pk1 >> BSHIFT) * 8 + q];
    float* a0 = &acc[(pk0 & (BNODES - 1)) * 33 + q * 4];
    float* a1 = &acc[(pk1 & (BNODES - 1)) * 33 + q * 4];
    atomicAdd(a0 + 0, v0.x); atomicAdd(a0 + 1, v0.y);
    atomicAdd(a0 + 2, v0.z); atomicAdd(a0 + 3, v0.w);
    atomicAdd(a1 + 0, v1.x); atomicAdd(a1 + 1, v1.y);
    atomicAdd(a1 + 2, v1.z); atomicAdd(a1 + 3, v1.w);
  }
  if (i < end) {
    int pk0 = order[i];
    float4 v0 = data[(size_t)(pk0 >> BSHIFT) * 8 + q];
    float* a0 = &acc[(pk0 & (BNODES - 1)) * 33 + q * 4];
    atomicAdd(a0 + 0, v0.x); atomicAdd(a0 + 1, v0.y);
    atomicAdd(a0 + 2, v0.z); atomicAdd(a0 + 3, v0.w);
  }
  __syncthreads();

  int nlocal = min(BNODES, N - lo);
  for (int t = threadIdx.x; t < nlocal * 8; t += K4_THREADS) {
    int r = t >> 3, jq = t & 7;
    const float* a = &acc[r * 33 + jq * 4];
    float4 v;
    v.x = a[0] * FACTOR; v.y = a[1] * FACTOR;
    v.z = a[2] * FACTOR; v.w = a[3] * FACTOR;
    out[(size_t)(lo + r) * 8 + jq] = v;
  }
}

// ---------- Fallback: round-1 atomic scatter ----------
__global__ void atomic_kernel(const float4* __restrict__ edge_data,
                              const int* __restrict__ edge_dst,
                              float* __restrict__ out, int E, int N) {
  int tid = blockIdx.x * blockDim.x + threadIdx.x;
  int e = tid >> 3;
  int q = tid & 7;
  if (e >= E) return;
  int dst = edge_dst[e];
  if (dst < 0 || dst >= N) return;
  float4 v = edge_data[(size_t)e * 8 + q];
  float* p = out + (size_t)dst * D + q * 4;
  unsafeAtomicAdd(p + 0, v.x * FACTOR);
  unsafeAtomicAdd(p + 1, v.y * FACTOR);
  unsafeAtomicAdd(p + 2, v.z * FACTOR);
  unsafeAtomicAdd(p + 3, v.w * FACTOR);
}

extern "C" void kernel_launch(void* const* d_in, const int* in_sizes, int n_in,
                              void* d_out, int out_size, void* d_ws, size_t ws_size,
                              hipStream_t stream) {
  const float4* edge_data = (const float4*)d_in[0];
  const int* edge_dst = (const int*)d_in[1];

  int E = in_sizes[1];
  int N = out_size / D;

  int nb = (N + BNODES - 1) >> BSHIFT;            // 782 for N=100K
  size_t need = ((size_t)3 * nb + (size_t)E) * sizeof(int);
  bool pack_ok = ((long long)E << BSHIFT) < (1ll << 31);

  if (nb > 1024 || ws_size < need || !pack_ok) {
    float* out = (float*)d_out;
    hipMemsetAsync(d_out, 0, (size_t)out_size * sizeof(float), stream);
    int total = E * 8;
    atomic_kernel<<<(total + 255) / 256, 256, 0, stream>>>(edge_data, edge_dst, out, E, N);
    return;
  }

  int* ws = (int*)d_ws;
  int* ghist  = ws;                // [nb]
  int* bases  = ws + nb;           // [nb]
  int* cursor = ws + 2 * nb;       // [nb]
  int* order  = ws + 3 * nb;       // [E]

  hipMemsetAsync(ghist, 0, (size_t)nb * sizeof(int), stream);

  size_t lds1 = (size_t)nb * sizeof(int);
  hist_kernel<<<256, 256, lds1, stream>>>(edge_dst, ghist, E, N, nb);

  scan_kernel<<<1, 1024, 0, stream>>>(ghist, bases, cursor, nb);

  int chunk = (E + 255) / 256;
  size_t lds3 = (size_t)2 * nb * sizeof(int);
  scatter_kernel<<<256, 256, lds3, stream>>>(edge_dst, cursor, order, E, N, nb, chunk);

  gather_kernel<<<nb, K4_THREADS, 0, stream>>>(
      edge_data, order, bases, ghist, (float4*)d_out, N);
}